// Round 3
// baseline (2265.321 us; speedup 1.0000x reference)
//
#include <hip/hip_runtime.h>

typedef unsigned short u16;
typedef __bf16 bf16x8 __attribute__((ext_vector_type(8)));
typedef short s16x8 __attribute__((ext_vector_type(8)));
typedef float f32x4 __attribute__((ext_vector_type(4)));

__device__ __forceinline__ float b2f(u16 u) {
  union { unsigned u32; float f; } x; x.u32 = ((unsigned)u) << 16; return x.f;
}
__device__ __forceinline__ u16 f2b(float f) {
  union { float f; unsigned u; } x; x.f = f;
  unsigned r = x.u + 0x7fffu + ((x.u >> 16) & 1u);
  return (u16)(r >> 16);
}

// Load 8 contiguous elements as bf16 bits; F32=1 converts from float (RNE).
template <int F32>
__device__ __forceinline__ s16x8 load8(const void* __restrict__ p, size_t idx) {
  if (F32) {
    const float* f = (const float*)p + idx;
    f32x4 a = *(const f32x4*)f;
    f32x4 b = *(const f32x4*)(f + 4);
    s16x8 r;
    r[0] = (short)f2b(a[0]); r[1] = (short)f2b(a[1]);
    r[2] = (short)f2b(a[2]); r[3] = (short)f2b(a[3]);
    r[4] = (short)f2b(b[0]); r[5] = (short)f2b(b[1]);
    r[6] = (short)f2b(b[2]); r[7] = (short)f2b(b[3]);
    return r;
  } else {
    return *(const s16x8*)((const u16*)p + idx);
  }
}

// ---------------------------------------------------------------------------
// MFMA bf16 GEMM: C[M,N] = act(A[M,K] * Bt[N,K]^T + bias[N]), f32 acc, bf16 out
// A/Bt are f32 (converted on stage) or bf16 per template. 128x128 tile, BK=32,
// 4 waves as 2x2 of 64x64. M%128==0, N%128==0, K%32==0. grid = (N/128, M/128)
// ---------------------------------------------------------------------------
template <int RELU, int AF32, int BF32>
__global__ __launch_bounds__(256) void gemm_bt_kernel(
    const void* __restrict__ A, const void* __restrict__ Bt,
    const float* __restrict__ bias, u16* __restrict__ C,
    int M, int N, int K) {
  __shared__ u16 As[128][32];
  __shared__ u16 Bs[128][32];
  const int tid = threadIdx.x;
  const int lane = tid & 63;
  const int wave = tid >> 6;
  const int wm = wave >> 1, wn = wave & 1;
  const int lr = tid >> 2;             // 0..63 (staging row, x2 halves)
  const int lk = (tid & 3) << 3;       // 0,8,16,24
  const int tn = blockIdx.x, tm = blockIdx.y;
  const size_t abase = (size_t)tm * 128 * K;
  const size_t bbase = (size_t)tn * 128 * K;
  const int fr = lane & 15;            // frag row/col
  const int fk = (lane >> 4) << 3;     // frag k offset
  f32x4 acc[4][4] = {};

  for (int k0 = 0; k0 < K; k0 += 32) {
    *(s16x8*)&As[lr][lk]      = load8<AF32>(A, abase + (size_t)lr * K + k0 + lk);
    *(s16x8*)&As[lr + 64][lk] = load8<AF32>(A, abase + (size_t)(lr + 64) * K + k0 + lk);
    *(s16x8*)&Bs[lr][lk]      = load8<BF32>(Bt, bbase + (size_t)lr * K + k0 + lk);
    *(s16x8*)&Bs[lr + 64][lk] = load8<BF32>(Bt, bbase + (size_t)(lr + 64) * K + k0 + lk);
    __syncthreads();
    bf16x8 af[4], bfv[4];
#pragma unroll
    for (int i = 0; i < 4; ++i)
      af[i] = __builtin_bit_cast(bf16x8, *(const s16x8*)&As[wm * 64 + i * 16 + fr][fk]);
#pragma unroll
    for (int j = 0; j < 4; ++j)
      bfv[j] = __builtin_bit_cast(bf16x8, *(const s16x8*)&Bs[wn * 64 + j * 16 + fr][fk]);
#pragma unroll
    for (int i = 0; i < 4; ++i)
#pragma unroll
      for (int j = 0; j < 4; ++j)
        acc[i][j] = __builtin_amdgcn_mfma_f32_16x16x32_bf16(af[i], bfv[j], acc[i][j], 0, 0, 0);
    __syncthreads();
  }

  // C/D layout: col = lane&15, row = (lane>>4)*4 + reg
  const int row0 = tm * 128 + wm * 64 + ((lane >> 4) << 2);
  const int col0 = tn * 128 + wn * 64 + fr;
#pragma unroll
  for (int j = 0; j < 4; ++j) {
    const int col = col0 + j * 16;
    const float bv = bias[col];
#pragma unroll
    for (int i = 0; i < 4; ++i) {
#pragma unroll
      for (int r = 0; r < 4; ++r) {
        float v = acc[i][j][r] + bv;
        if (RELU) v = fmaxf(v, 0.f);
        C[(size_t)(row0 + i * 16 + r) * N + col] = f2b(v);
      }
    }
  }
}

// ---------------------------------------------------------------------------
__device__ __forceinline__ void block_stats(float s, float s2, float* red, int tid,
                                            float& S, float& S2) {
#pragma unroll
  for (int o = 32; o > 0; o >>= 1) { s += __shfl_xor(s, o); s2 += __shfl_xor(s2, o); }
  if ((tid & 63) == 0) { red[tid >> 6] = s; red[4 + (tid >> 6)] = s2; }
  __syncthreads();
  S = red[0] + red[1] + red[2] + red[3];
  S2 = red[4] + red[5] + red[6] + red[7];
}

// t = LN(2*y) with ln1 params; batch-invariant (100 x 768), f32 in/out
__global__ __launch_bounds__(256) void t_kernel(const float* __restrict__ y,
                                                const float* __restrict__ g,
                                                const float* __restrict__ bb,
                                                float* __restrict__ t) {
  const int l = blockIdx.x, tid = threadIdx.x;
  __shared__ float red[8];
  float xv[3], s = 0.f, s2 = 0.f;
#pragma unroll
  for (int i = 0; i < 3; ++i) {
    int e = tid + i * 256;
    float v = 2.f * y[(size_t)l * 768 + e];
    xv[i] = v; s += v; s2 += v * v;
  }
  float S, S2;
  block_stats(s, s2, red, tid, S, S2);
  float mean = S * (1.f / 768.f);
  float var = S2 * (1.f / 768.f) - mean * mean;
  float inv = rsqrtf(var + 1e-5f);
#pragma unroll
  for (int i = 0; i < 3; ++i) {
    int e = tid + i * 256;
    t[(size_t)l * 768 + e] = (xv[i] - mean) * inv * g[e] + bb[e];
  }
}

// q = t @ Wq^T + bq  (100 x 768, K=768), all f32. block per l.
__global__ __launch_bounds__(256) void q_kernel(const float* __restrict__ t,
                                                const float* __restrict__ Wq,
                                                const float* __restrict__ bq,
                                                float* __restrict__ q) {
  const int l = blockIdx.x, tid = threadIdx.x;
  __shared__ __align__(16) float ts[768];
  for (int i = tid; i < 768; i += 256) ts[i] = t[(size_t)l * 768 + i];
  __syncthreads();
  for (int e = tid; e < 768; e += 256) {
    const float* wr = Wq + (size_t)e * 768;
    float acc = bq[e];
    for (int j = 0; j < 768; j += 4) {
      f32x4 wv = *(const f32x4*)&wr[j];
      f32x4 tv = *(const f32x4*)&ts[j];
      acc += wv[0] * tv[0] + wv[1] * tv[1] + wv[2] * tv[2] + wv[3] * tv[3];
    }
    q[(size_t)l * 768 + e] = acc;
  }
}

// c2[l][j] = sum_d y[l,d] * pool[l, 768+d, j] + dup_bias[l*10+j]   (100 x 10)
__global__ __launch_bounds__(256) void c2_kernel(const float* __restrict__ y,
                                                 const float* __restrict__ pool,
                                                 const float* __restrict__ dbias,
                                                 float* __restrict__ c2) {
  const int l = blockIdx.x, tid = threadIdx.x, lane = tid & 63, w = tid >> 6;
  for (int j = w; j < 10; j += 4) {
    float acc = 0.f;
    for (int d = lane; d < 768; d += 64)
      acc += y[(size_t)l * 768 + d] * pool[((size_t)l * 1536 + 768 + d) * 10 + j];
#pragma unroll
    for (int o = 32; o > 0; o >>= 1) acc += __shfl_xor(acc, o);
    if (lane == 0) c2[l * 10 + j] = acc + dbias[l * 10 + j];
  }
}

// ---------------------------------------------------------------------------
// Fused cross-attention. block = (b, l-tile of 5). Loops h=0..7:
//   scores (5x1024, LDS f32) -> softmax -> asum += attn ; ao_h = attn @ v_h
// Writes ao (3200x768 bf16) and a_score = asum/8 (f32, directly into d_out).
// ---------------------------------------------------------------------------
__global__ __launch_bounds__(256) void attn_kernel(
    const float* __restrict__ q,      // 100 x 768 f32
    const u16* __restrict__ kmat,     // 32768 x 768 bf16
    const u16* __restrict__ vmat,     // 32768 x 768 bf16
    u16* __restrict__ ao,             // 3200 x 768 bf16
    float* __restrict__ ascore) {     // (32*100) x 1024 f32
  const int b = blockIdx.x;
  const int l0 = blockIdx.y * 5;
  __shared__ float sc[5][1024];                    // 20480 B
  __shared__ float asum[5][1024];                  // 20480 B
  __shared__ __align__(16) u16 kv[64][104];        // 13312 B (row stride 208 B)
  __shared__ __align__(16) float qs[5][96];        // 1920 B
  const int tid = threadIdx.x, lane = tid & 63, w = tid >> 6;
  float* pa = &asum[0][0];
  float* psc = &sc[0][0];
  for (int i = tid; i < 5 * 1024; i += 256) pa[i] = 0.f;

  for (int h = 0; h < 8; ++h) {
    for (int i = tid; i < 480; i += 256) {
      int r = i / 96, d = i % 96;
      qs[r][d] = q[(size_t)(l0 + r) * 768 + h * 96 + d];
    }
    __syncthreads();
    // ---- scores ----
    for (int st = 0; st < 16; ++st) {
      const int s0 = st * 64;
      for (int i = tid; i < 768; i += 256) {    // 64 rows x 12 chunks of 8
        int sr = i / 12, off = (i % 12) * 8;
        *(s16x8*)&kv[sr][off] =
            *(const s16x8*)&kmat[(size_t)(b * 1024 + s0 + sr) * 768 + h * 96 + off];
      }
      __syncthreads();
      for (int idx = tid; idx < 320; idx += 256) {
        int r = idx >> 6, c = idx & 63;
        float dot = 0.f;
#pragma unroll
        for (int j = 0; j < 96; j += 8) {
          s16x8 kk = *(const s16x8*)&kv[c][j];
          f32x4 qa = *(const f32x4*)&qs[r][j];
          f32x4 qb = *(const f32x4*)&qs[r][j + 4];
          dot += b2f((u16)kk[0]) * qa[0] + b2f((u16)kk[1]) * qa[1] +
                 b2f((u16)kk[2]) * qa[2] + b2f((u16)kk[3]) * qa[3] +
                 b2f((u16)kk[4]) * qb[0] + b2f((u16)kk[5]) * qb[1] +
                 b2f((u16)kk[6]) * qb[2] + b2f((u16)kk[7]) * qb[3];
        }
        sc[r][s0 + c] = dot * 0.10206207261596575f;  // 1/sqrt(96)
      }
      __syncthreads();
    }
    // ---- softmax (wave w owns rows w, w+4) ----
    for (int r = w; r < 5; r += 4) {
      float m = -1e30f;
      for (int i = lane; i < 1024; i += 64) m = fmaxf(m, sc[r][i]);
#pragma unroll
      for (int o = 32; o > 0; o >>= 1) m = fmaxf(m, __shfl_xor(m, o));
      float sum = 0.f;
      for (int i = lane; i < 1024; i += 64) {
        float e = __expf(sc[r][i] - m);
        sc[r][i] = e; sum += e;
      }
#pragma unroll
      for (int o = 32; o > 0; o >>= 1) sum += __shfl_xor(sum, o);
      float inv = 1.f / sum;
      for (int i = lane; i < 1024; i += 64) sc[r][i] *= inv;
    }
    __syncthreads();
    for (int i = tid; i < 5 * 1024; i += 256) pa[i] += psc[i];
    // ---- ao_h = attn @ v_h ----
    float acc0 = 0.f, acc1 = 0.f;
    const int r0 = tid / 96, d0 = tid % 96;
    const int r1 = (tid + 256) / 96, d1 = (tid + 256) % 96;
    for (int st = 0; st < 16; ++st) {
      const int s0 = st * 64;
      __syncthreads();
      for (int i = tid; i < 768; i += 256) {
        int sr = i / 12, off = (i % 12) * 8;
        *(s16x8*)&kv[sr][off] =
            *(const s16x8*)&vmat[(size_t)(b * 1024 + s0 + sr) * 768 + h * 96 + off];
      }
      __syncthreads();
      {
        float a = 0.f;
#pragma unroll 8
        for (int s = 0; s < 64; ++s) a += sc[r0][s0 + s] * b2f(kv[s][d0]);
        acc0 += a;
      }
      if (tid < 224) {
        float a = 0.f;
#pragma unroll 8
        for (int s = 0; s < 64; ++s) a += sc[r1][s0 + s] * b2f(kv[s][d1]);
        acc1 += a;
      }
    }
    ao[(size_t)(b * 100 + l0 + r0) * 768 + h * 96 + d0] = f2b(acc0);
    if (tid < 224)
      ao[(size_t)(b * 100 + l0 + r1) * 768 + h * 96 + d1] = f2b(acc1);
    __syncthreads();
  }
  for (int i = tid; i < 5 * 1024; i += 256) {
    int r = i >> 10, s = i & 1023;
    ascore[(size_t)(b * 100 + l0 + r) * 1024 + s] = asum[r][s] * 0.125f;
  }
}

// ---------------------------------------------------------------------------
// out = LN(base + add) ; base f32 (per-l if flag, else per-row), add bf16.
// g/b f32. Writes f32 (optional) and bf16 (optional). block per row (3200).
// ---------------------------------------------------------------------------
__global__ __launch_bounds__(256) void ln_kernel(
    const float* __restrict__ base, const u16* __restrict__ add,
    const float* __restrict__ g, const float* __restrict__ bb,
    float* __restrict__ outf, u16* __restrict__ outb, int base_per_l) {
  const int row = blockIdx.x, tid = threadIdx.x;
  __shared__ float red[8];
  const size_t boff = (size_t)(base_per_l ? (row % 100) : row) * 768;
  const size_t aoff = (size_t)row * 768;
  float xv[3], s = 0.f, s2 = 0.f;
#pragma unroll
  for (int i = 0; i < 3; ++i) {
    int e = tid + i * 256;
    float v = base[boff + e] + b2f(add[aoff + e]);
    xv[i] = v; s += v; s2 += v * v;
  }
  float S, S2;
  block_stats(s, s2, red, tid, S, S2);
  float mean = S * (1.f / 768.f);
  float var = S2 * (1.f / 768.f) - mean * mean;
  float inv = rsqrtf(var + 1e-5f);
#pragma unroll
  for (int i = 0; i < 3; ++i) {
    int e = tid + i * 256;
    float o = (xv[i] - mean) * inv * g[e] + bb[e];
    if (outf) outf[aoff + e] = o;
    if (outb) outb[aoff + e] = f2b(o);
  }
}

// ---------------------------------------------------------------------------
// logits[b, l*10+j] = sum_{d<768} h[b,l,d] * pool[l,d,j] + c2[l,j]. block per l.
// Writes f32 directly into d_out.
// ---------------------------------------------------------------------------
__global__ __launch_bounds__(256) void groupfc_kernel(
    const u16* __restrict__ h, const float* __restrict__ pool,
    const float* __restrict__ c2, float* __restrict__ logits) {
  const int l = blockIdx.x, tid = threadIdx.x;
  __shared__ float ps[768][10];
  for (int i = tid; i < 7680; i += 256) ps[i / 10][i % 10] = pool[(size_t)l * 15360 + i];
  __syncthreads();
  for (int idx = tid; idx < 320; idx += 256) {
    int bb = idx / 10, j = idx % 10;
    const u16* hr = h + (size_t)(bb * 100 + l) * 768;
    float acc = c2[l * 10 + j];
    for (int d0 = 0; d0 < 768; d0 += 8) {
      s16x8 hv = *(const s16x8*)&hr[d0];
#pragma unroll
      for (int e = 0; e < 8; ++e) acc += b2f((u16)hv[e]) * ps[d0 + e][j];
    }
    logits[bb * 1000 + l * 10 + j] = acc;
  }
}

// ---------------------------------------------------------------------------
extern "C" void kernel_launch(void* const* d_in, const int* in_sizes, int n_in,
                              void* d_out, int out_size, void* d_ws, size_t ws_size,
                              hipStream_t stream) {
  (void)in_sizes; (void)n_in; (void)out_size; (void)ws_size;
  const float* x      = (const float*)d_in[0];
  const float* y      = (const float*)d_in[1];
  const float* embedW = (const float*)d_in[2];
  const float* embedb = (const float*)d_in[3];
  const float* Wq     = (const float*)d_in[4];
  const float* Wk     = (const float*)d_in[5];
  const float* Wv     = (const float*)d_in[6];
  const float* bq     = (const float*)d_in[7];
  const float* bk     = (const float*)d_in[8];
  const float* bv     = (const float*)d_in[9];
  const float* Wo     = (const float*)d_in[10];
  const float* bo     = (const float*)d_in[11];
  const float* ln1g   = (const float*)d_in[12];
  const float* ln1b   = (const float*)d_in[13];
  const float* ln2g   = (const float*)d_in[14];
  const float* ln2b   = (const float*)d_in[15];
  const float* ln3g   = (const float*)d_in[16];
  const float* ln3b   = (const float*)d_in[17];
  const float* W1     = (const float*)d_in[18];
  const float* b1     = (const float*)d_in[19];
  const float* W2     = (const float*)d_in[20];
  const float* b2     = (const float*)d_in[21];
  const float* pool   = (const float*)d_in[22];
  const float* dbias  = (const float*)d_in[23];

  // Workspace layout (peak ~151.6 MB): kws | vws | R(mem, then post-attn) | small
  char* w = (char*)d_ws;
  u16* kws = (u16*)(w);                         // 50,331,648 B
  u16* vws = (u16*)(w + 50331648);              // 50,331,648 B
  char* R  = w + 100663296;                     // 50,331,648 B region
  u16*   mem = (u16*)R;                         // dead after V-projection
  u16*   ao  = (u16*)(R + 0);
  u16*   u1  = (u16*)(R + 4915200);
  u16*   t2b = (u16*)(R + 9830400);
  u16*   f1  = (u16*)(R + 14745600);
  u16*   f2  = (u16*)(R + 19660800);
  u16*   hb  = (u16*)(R + 24576000);
  float* t2f = (float*)(R + 29491200);          // +9,830,400 B ends at 39,321,600
  float* tf  = (float*)(w + 150994944);
  float* qf  = (float*)(w + 150994944 + 307200);
  float* c2  = (float*)(w + 150994944 + 614400);

  float* logits = (float*)d_out;
  float* ascore = (float*)d_out + 32000;

  t_kernel<<<dim3(100), dim3(256), 0, stream>>>(y, ln1g, ln1b, tf);
  q_kernel<<<dim3(100), dim3(256), 0, stream>>>(tf, Wq, bq, qf);
  c2_kernel<<<dim3(100), dim3(256), 0, stream>>>(y, pool, dbias, c2);

  gemm_bt_kernel<1, 1, 1><<<dim3(6, 256), dim3(256), 0, stream>>>(x, embedW, embedb, mem, 32768, 768, 2048);
  gemm_bt_kernel<0, 0, 1><<<dim3(6, 256), dim3(256), 0, stream>>>(mem, Wk, bk, kws, 32768, 768, 768);
  gemm_bt_kernel<0, 0, 1><<<dim3(6, 256), dim3(256), 0, stream>>>(mem, Wv, bv, vws, 32768, 768, 768);

  attn_kernel<<<dim3(32, 20), dim3(256), 0, stream>>>(qf, kws, vws, ao, ascore);

  gemm_bt_kernel<0, 0, 1><<<dim3(6, 25), dim3(256), 0, stream>>>(ao, Wo, bo, u1, 3200, 768, 768);
  ln_kernel<<<dim3(3200), dim3(256), 0, stream>>>(tf, u1, ln2g, ln2b, t2f, t2b, 1);
  gemm_bt_kernel<1, 0, 1><<<dim3(6, 25), dim3(256), 0, stream>>>(t2b, W1, b1, f1, 3200, 768, 768);
  gemm_bt_kernel<0, 0, 1><<<dim3(6, 25), dim3(256), 0, stream>>>(f1, W2, b2, f2, 3200, 768, 768);
  ln_kernel<<<dim3(3200), dim3(256), 0, stream>>>(t2f, f2, ln3g, ln3b, (float*)nullptr, hb, 0);
  groupfc_kernel<<<dim3(100), dim3(256), 0, stream>>>(hb, pool, c2, logits);
}